// Round 6
// baseline (105.140 us; speedup 1.0000x reference)
//
#include <hip/hip_runtime.h>

#define WSTRIDE 8704              // padded row stride for wab & partials
#define PSZ (128 * WSTRIDE)       // one partial buffer (floats)

__device__ __forceinline__ float lrelu(float x) { return x > 0.0f ? x : 0.01f * x; }

// h0T[j][b] = lrelu(sum_l z[b][l]*W0[l][j] + b0[j]); one block per j, lane = b
__global__ __launch_bounds__(128) void h0T_kernel(const float* __restrict__ z,
                                                  const float* __restrict__ W,
                                                  const float* __restrict__ bias,
                                                  float* __restrict__ h0T) {
    int j = blockIdx.x;          // 0..511
    int b = threadIdx.x;         // 0..127
    float zr[16];
    *(float4*)&zr[0]  = *(const float4*)&z[b * 16 + 0];
    *(float4*)&zr[4]  = *(const float4*)&z[b * 16 + 4];
    *(float4*)&zr[8]  = *(const float4*)&z[b * 16 + 8];
    *(float4*)&zr[12] = *(const float4*)&z[b * 16 + 12];
    float acc = bias[j];
#pragma unroll
    for (int l = 0; l < 16; ++l) acc = fmaf(zr[l], W[l * 512 + j], acc);
    h0T[j * 128 + b] = lrelu(acc);
}

// OT[j][b] = lrelu(sum_k At[k][b]*W[k][j] + bias[j]); unchanged from R5.
__global__ __launch_bounds__(512) void gemmT_kernel(const float* __restrict__ At,
                                                    const float* __restrict__ W,
                                                    const float* __restrict__ bias,
                                                    float* __restrict__ OT) {
    __shared__ __align__(16) float As[512][4];
    __shared__ float red[8][64][5];
    int jt = blockIdx.x & 7;
    int bt = blockIdx.x >> 3;
    int tid = threadIdx.x;
    int lane = tid & 63;
    int wid  = __builtin_amdgcn_readfirstlane(tid >> 6);
    int b0 = bt * 4;
#pragma unroll
    for (int r = 0; r < 2; ++r) {
        int p = r * 512 + tid;
        int k = p >> 1, q = p & 1;
        *(float2*)&As[k][q * 2] = *(const float2*)&At[k * 128 + b0 + q * 2];
    }
    __syncthreads();
    int j = jt * 64 + lane;
    float acc[4] = {};
    int k0 = wid * 64;
#pragma unroll 8
    for (int kk = 0; kk < 64; ++kk) {
        int k = k0 + kk;
        float4 a = *(const float4*)&As[k][0];
        float w = W[k * 512 + j];
        acc[0] = fmaf(a.x, w, acc[0]);
        acc[1] = fmaf(a.y, w, acc[1]);
        acc[2] = fmaf(a.z, w, acc[2]);
        acc[3] = fmaf(a.w, w, acc[3]);
    }
#pragma unroll
    for (int i = 0; i < 4; ++i) red[wid][lane][i] = acc[i];
    __syncthreads();
    if (tid < 256) {
        int jj = tid >> 2;
        int bb = tid & 3;
        float s = 0.f;
#pragma unroll
        for (int w = 0; w < 8; ++w) s += red[w][jj][bb];
        int jg = jt * 64 + jj;
        OT[jg * 128 + b0 + bb] = lrelu(s + bias[jg]);
    }
}

// ---- wabT helpers ----
__device__ __forceinline__ void ldk(const float (*Asw)[16], const float* Wp, int kk,
                                    float (&a)[16], float (&w)[8]) {
    float4 t0 = *(const float4*)&Asw[kk][0];
    float4 t1 = *(const float4*)&Asw[kk][4];
    float4 t2 = *(const float4*)&Asw[kk][8];
    float4 t3 = *(const float4*)&Asw[kk][12];
    a[0]=t0.x; a[1]=t0.y; a[2]=t0.z; a[3]=t0.w;
    a[4]=t1.x; a[5]=t1.y; a[6]=t1.z; a[7]=t1.w;
    a[8]=t2.x; a[9]=t2.y; a[10]=t2.z; a[11]=t2.w;
    a[12]=t3.x; a[13]=t3.y; a[14]=t3.z; a[15]=t3.w;
    const float* wr = Wp + (size_t)kk * 8450;
    float2 u0 = *(const float2*)&wr[0];   // j0 even -> 8B aligned always
    float2 u1 = *(const float2*)&wr[2];
    float2 u2 = *(const float2*)&wr[4];
    float2 u3 = *(const float2*)&wr[6];
    w[0]=u0.x; w[1]=u0.y; w[2]=u1.x; w[3]=u1.y;
    w[4]=u2.x; w[5]=u2.y; w[6]=u3.x; w[7]=u3.y;
}
__device__ __forceinline__ void fmak(const float (&a)[16], const float (&w)[8],
                                     float (&acc)[16][8]) {
#pragma unroll
    for (int i = 0; i < 16; ++i)
#pragma unroll
        for (int j = 0; j < 8; ++j)
            acc[i][j] = fmaf(a[i], w[j], acc[i][j]);
}

// parts[p][b][j] : p = kh*4+wid k-slice partial of At^T @ hWo (no bias).
// Main 256 blocks: 16 jt (512 j, jl=8) x 8 bt (16 b) x 2 kh; XCD-grouped
// (bx%8 == jt%8 so each jt's 1MB W slice stays in one XCD L2).
// Tail 16 blocks (bx>=256): j 8192..8449 with clamped scalar loads.
__global__ __launch_bounds__(256) void wabT_kernel(const float* __restrict__ At,
                                                   const float* __restrict__ W,
                                                   float* __restrict__ parts) {
    __shared__ __align__(16) float As[256][16];   // 16 KB
    int tid = threadIdx.x;
    int lane = tid & 63;
    int wid = __builtin_amdgcn_readfirstlane(tid >> 6);
    int jt, bt, kh;
    bool tail = blockIdx.x >= 256;
    if (!tail) {
        int x = blockIdx.x & 7, w = blockIdx.x >> 3;
        jt = x + 8 * (w >> 4);
        bt = (w >> 1) & 7;
        kh = w & 1;
    } else {
        int r = blockIdx.x - 256;
        jt = 16; bt = r >> 1; kh = r & 1;
    }
    int b0 = bt * 16;
    int k0b = kh * 256;
    // stage At[k0b..+255][b0..+15] -> As (coalesced float4)
#pragma unroll
    for (int r = 0; r < 4; ++r) {
        int p = r * 256 + tid;
        int k = p >> 2, q = p & 3;
        *(float4*)&As[k][q * 4] = *(const float4*)&At[(k0b + k) * 128 + b0 + q * 4];
    }
    __syncthreads();
    int kw = wid * 64;
    int j0 = jt * 512 + lane * 8;
    float acc[16][8];
#pragma unroll
    for (int i = 0; i < 16; ++i)
#pragma unroll
        for (int j = 0; j < 8; ++j) acc[i][j] = 0.0f;
    const float (*Asw)[16] = (const float (*)[16])&As[kw];

    if (!tail) {
        const float* Wp = W + (size_t)(k0b + kw) * 8450 + j0;
        float aA[16], wA[8], aB[16], wB[8];
        ldk(Asw, Wp, 0, aA, wA);
        ldk(Asw, Wp, 1, aB, wB);
        for (int kk = 0; kk < 62; kk += 2) {
            fmak(aA, wA, acc);
            ldk(Asw, Wp, kk + 2, aA, wA);
            fmak(aB, wB, acc);
            if (kk + 3 < 64) ldk(Asw, Wp, kk + 3, aB, wB);
        }
        fmak(aA, wA, acc);   // kk = 62
        fmak(aB, wB, acc);   // kk = 63
        size_t pbase = (size_t)(kh * 4 + wid) * PSZ;
#pragma unroll
        for (int bb = 0; bb < 16; ++bb) {
            float* d = parts + pbase + (size_t)(b0 + bb) * WSTRIDE + j0;
            *(float4*)&d[0] = make_float4(acc[bb][0], acc[bb][1], acc[bb][2], acc[bb][3]);
            *(float4*)&d[4] = make_float4(acc[bb][4], acc[bb][5], acc[bb][6], acc[bb][7]);
        }
    } else if (j0 < 8450) {
        for (int kk = 0; kk < 64; ++kk) {
            const float* wr = W + (size_t)(k0b + kw + kk) * 8450;
            float w[8];
#pragma unroll
            for (int e = 0; e < 8; ++e) {
                int j = j0 + e;
                w[e] = wr[j < 8450 ? j : 8449];
            }
            float a[16];
#pragma unroll
            for (int i = 0; i < 16; ++i) a[i] = Asw[kk][i];
            fmak(a, w, acc);
        }
        size_t pbase = (size_t)(kh * 4 + wid) * PSZ;
#pragma unroll
        for (int bb = 0; bb < 16; ++bb)
#pragma unroll
            for (int e = 0; e < 8; ++e)
                if (j0 + e < 8450)
                    parts[pbase + (size_t)(b0 + bb) * WSTRIDE + j0 + e] = acc[bb][e];
    }
}

// wabF[b][dest(j)] = sum_p parts[p][b][j] + bias[j]; dest(j) = j + (j>=65 ? 3 : 0)
// (the +3 shift 16B-aligns W1/W2 rows for the decoder's float4 loads)
__global__ __launch_bounds__(256) void add_kernel(const float* __restrict__ parts,
                                                  const float* __restrict__ bias,
                                                  float* __restrict__ wab) {
    int q = blockIdx.x * 256 + threadIdx.x;
    if (q >= 2113) return;
    int b = blockIdx.y;
    int j0 = q * 4;
    size_t off = (size_t)b * WSTRIDE + j0;
    float s[4] = {0.f, 0.f, 0.f, 0.f};
#pragma unroll
    for (int p = 0; p < 8; ++p) {
        float4 v = *(const float4*)&parts[(size_t)p * PSZ + off];
        s[0] += v.x; s[1] += v.y; s[2] += v.z; s[3] += v.w;
    }
    float* drow = wab + (size_t)b * WSTRIDE;
#pragma unroll
    for (int e = 0; e < 4; ++e) {
        int j = j0 + e;
        if (j < 8450)
            drow[j + (j >= 65 ? 3 : 0)] = s[e] + bias[j];
    }
}

// Decoder. wabF row layout (post-shift): w0[0:64], b0[64], pad[65:68),
// W1[68:4164), b1[4164:4228), W2[4228:8324), b2[8324:8388), w3[8388:8452), b3[8452].
// lane = g, jq = wave's 16-j slice. W read straight from global (uniform-address
// vector loads -> VMEM broadcast, vmcnt-pipelined; LDS only holds h state).
__global__ __launch_bounds__(256) void decoder_kernel(const float* __restrict__ wab,
                                                      const float* __restrict__ logP,
                                                      float* __restrict__ out) {
    __shared__ float hX[64 * 65];
    __shared__ float hY[64 * 65];
    __shared__ float red[4][68];
    int b  = blockIdx.x >> 1;
    int gh = blockIdx.x & 1;
    int tid = threadIdx.x;
    int lane = tid & 63;
    int jq = (tid >> 6) * 16;   // NOT readfirstlane: keeps W loads on the vector path
    int g = gh * 64 + lane;
    bool act = g < 100;
    const float* __restrict__ row = wab + (size_t)b * WSTRIDE;
    float x0 = act ? logP[b * 100 + g] * (1.0f / 3.0f) : 0.0f;
    float c0 = row[64];
#pragma unroll
    for (int t = 0; t < 16; ++t)
        hX[(jq + t) * 65 + lane] = __sinf(30.0f * fmaf(x0, row[jq + t], c0));
    __syncthreads();
    // layer 1: hY[j][g] = sin(sum_i hX[i][g]*W1[i][j] + b1[j])
    {
        float a[16];
#pragma unroll
        for (int t = 0; t < 16; ++t) a[t] = row[4164 + jq + t];
#pragma unroll 4
        for (int i = 0; i < 64; ++i) {
            float hi = hX[i * 65 + lane];
            const float* wr = row + 68 + i * 64 + jq;   // 16B aligned
            float4 w0 = *(const float4*)&wr[0];
            float4 w1 = *(const float4*)&wr[4];
            float4 w2 = *(const float4*)&wr[8];
            float4 w3 = *(const float4*)&wr[12];
            a[0]  = fmaf(hi, w0.x, a[0]);  a[1]  = fmaf(hi, w0.y, a[1]);
            a[2]  = fmaf(hi, w0.z, a[2]);  a[3]  = fmaf(hi, w0.w, a[3]);
            a[4]  = fmaf(hi, w1.x, a[4]);  a[5]  = fmaf(hi, w1.y, a[5]);
            a[6]  = fmaf(hi, w1.z, a[6]);  a[7]  = fmaf(hi, w1.w, a[7]);
            a[8]  = fmaf(hi, w2.x, a[8]);  a[9]  = fmaf(hi, w2.y, a[9]);
            a[10] = fmaf(hi, w2.z, a[10]); a[11] = fmaf(hi, w2.w, a[11]);
            a[12] = fmaf(hi, w3.x, a[12]); a[13] = fmaf(hi, w3.y, a[13]);
            a[14] = fmaf(hi, w3.z, a[14]); a[15] = fmaf(hi, w3.w, a[15]);
        }
#pragma unroll
        for (int t = 0; t < 16; ++t) hY[(jq + t) * 65 + lane] = __sinf(a[t]);
    }
    __syncthreads();
    // layer 2: hX[j][g] = sin(sum_i hY[i][g]*W2[i][j] + b2[j])
    {
        float a[16];
#pragma unroll
        for (int t = 0; t < 16; ++t) a[t] = row[8324 + jq + t];
#pragma unroll 4
        for (int i = 0; i < 64; ++i) {
            float hi = hY[i * 65 + lane];
            const float* wr = row + 4228 + i * 64 + jq;
            float4 w0 = *(const float4*)&wr[0];
            float4 w1 = *(const float4*)&wr[4];
            float4 w2 = *(const float4*)&wr[8];
            float4 w3 = *(const float4*)&wr[12];
            a[0]  = fmaf(hi, w0.x, a[0]);  a[1]  = fmaf(hi, w0.y, a[1]);
            a[2]  = fmaf(hi, w0.z, a[2]);  a[3]  = fmaf(hi, w0.w, a[3]);
            a[4]  = fmaf(hi, w1.x, a[4]);  a[5]  = fmaf(hi, w1.y, a[5]);
            a[6]  = fmaf(hi, w1.z, a[6]);  a[7]  = fmaf(hi, w1.w, a[7]);
            a[8]  = fmaf(hi, w2.x, a[8]);  a[9]  = fmaf(hi, w2.y, a[9]);
            a[10] = fmaf(hi, w2.z, a[10]); a[11] = fmaf(hi, w2.w, a[11]);
            a[12] = fmaf(hi, w3.x, a[12]); a[13] = fmaf(hi, w3.y, a[13]);
            a[14] = fmaf(hi, w3.z, a[14]); a[15] = fmaf(hi, w3.w, a[15]);
        }
#pragma unroll
        for (int t = 0; t < 16; ++t) hX[(jq + t) * 65 + lane] = __sinf(a[t]);
    }
    __syncthreads();
    // layer 3
    float p = 0.f;
#pragma unroll
    for (int t = 0; t < 16; ++t)
        p = fmaf(hX[(jq + t) * 65 + lane], row[8388 + jq + t], p);
    red[tid >> 6][lane] = p;
    __syncthreads();
    if (tid < 64 && act) {
        float s = red[0][lane] + red[1][lane] + red[2][lane] + red[3][lane] + row[8452];
        out[b * 100 + g] = fmaf(s, 500.0f, 1500.0f);
    }
}

extern "C" void kernel_launch(void* const* d_in, const int* in_sizes, int n_in,
                              void* d_out, int out_size, void* d_ws, size_t ws_size,
                              hipStream_t stream) {
    const float* z    = (const float*)d_in[0];
    const float* logP = (const float*)d_in[1];
    const float* hW0  = (const float*)d_in[2];
    const float* hb0  = (const float*)d_in[3];
    const float* hW1  = (const float*)d_in[4];
    const float* hb1  = (const float*)d_in[5];
    const float* hW2  = (const float*)d_in[6];
    const float* hb2  = (const float*)d_in[7];
    const float* hWo  = (const float*)d_in[8];
    const float* hbo  = (const float*)d_in[9];
    float* out = (float*)d_out;

    float* parts = (float*)d_ws;                  // 8 * PSZ floats (35.7 MB)
    float* wabF  = parts + 8 * (size_t)PSZ;       // PSZ floats
    float* h0T   = wabF + PSZ;                    // 512*128
    float* h1T   = h0T + 512 * 128;
    float* h2T   = h1T + 512 * 128;               // total ~41 MB of d_ws

    h0T_kernel<<<512, 128, 0, stream>>>(z, hW0, hb0, h0T);
    gemmT_kernel<<<256, 512, 0, stream>>>(h0T, hW1, hb1, h1T);
    gemmT_kernel<<<256, 512, 0, stream>>>(h1T, hW2, hb2, h2T);
    wabT_kernel<<<272, 256, 0, stream>>>(h2T, hWo, parts);
    add_kernel<<<dim3(9, 128), 256, 0, stream>>>(parts, hbo, wabF);
    decoder_kernel<<<256, 256, 0, stream>>>(wabF, logP, out);
}